// Round 2
// baseline (301.790 us; speedup 1.0000x reference)
//
#include <hip/hip_runtime.h>
#include <math.h>

// SIFA fused, MFMA v5.
// v4 was VALU-issue-bound in k_main (~1000 VALU-cyc/thread-iter: conv FMA +
// gate transcendentals + pack/swizzle welded into the barrier-locked MFMA
// loop at ~7 waves/CU). v5 splits: k_apply computes gated-u once and writes a
// pre-packed f16 B-image in MFMA fragment order [b][tile][kb][px][8]; k_main
// is a pure streaming GEMM (A,B frags straight from global, no LDS tiles, no
// loop barriers). K packs 4 chans x 9j -> 40 slots (K=640, was 1024 w/ pads).
// ws may be small: launcher chunks batches {8,4,2,1} x 21MB B-image buffer.

#define EPSF 1e-5f
typedef _Float16 v8h __attribute__((ext_vector_type(8)));
typedef __fp16 fp16x2 __attribute__((ext_vector_type(2)));   // cvt_pkrtz native type
typedef float v4f __attribute__((ext_vector_type(4)));

static constexpr int C_ = 64, HW_ = 16384, W_ = 128;
static constexpr int KB_ = 80;                 // K = 640 = 80 cells of 8 f16

// ws float offsets
static constexpr int WS_WFOLD = 0;      // 5184: [c][j][k] folded depthwise weights
static constexpr int WS_SHIFT = 5184;   // 576
static constexpr int WS_BIAS  = 5760;   // 128
static constexpr int WS_GATE  = 5888;   // 512*4 {wa*cgate, 1-wa, -log2e*a_sp, -log2e*b_sp}
static constexpr int WS_PART  = 7936;   // 2048*2 partial sums
static constexpr int WS_WH    = 12032;  // 80*128*8 f16 = 40960 floats: Wh[kb][oup][8]
static constexpr int WS_BIMG  = 52992;  // B-image: per batch 128tile*80kb*128px*8 f16
static constexpr size_t BIMG_BATCH_F16 = (size_t)128 * KB_ * 128 * 8;   // 10,485,760
static constexpr size_t BIMG_BATCH_FLT = BIMG_BATCH_F16 / 2;            // 5,242,880

__device__ __forceinline__ float sigmf(float v) { return 1.f / (1.f + __expf(-v)); }

// K-slot mapping: k = grp*80 + tp*40 + vv, grp=c>>3, tp=(c>>2)&1, vv = j*4 + (c&3)
// (vv 36..39 are zero pads). Shared by k_fold (A) and k_apply (B).
__global__ __launch_bounds__(256) void k_fold(
    const float* __restrict__ gen_w,
    const float* __restrict__ gg, const float* __restrict__ gb,
    const float* __restrict__ gm, const float* __restrict__ gv,
    const float* __restrict__ conv_w,
    const float* __restrict__ cg, const float* __restrict__ cb,
    const float* __restrict__ cm, const float* __restrict__ cv,
    float* __restrict__ ws)
{
    int idx = blockIdx.x * 256 + threadIdx.x;
    _Float16* Whp = (_Float16*)(ws + WS_WH);
    if (idx < 81920) {
        // fragment layout: idx = (kb*128 + oup)*8 + e; K index k = kb*8+e
        int kb = idx >> 10, oup = (idx >> 3) & 127, e = idx & 7;
        int k = kb * 8 + e;
        int grp = k / 80, rr = k - grp * 80;
        int tp = rr / 40, vv = rr - tp * 40;
        float v = 0.f;
        if (vv < 36) {
            int j = vv >> 2, cl = vv & 3, c = grp * 8 + tp * 4 + cl;
            float s = cg[oup] * rsqrtf(cv[oup] + EPSF);
            v = conv_w[(oup * C_ + c) * 9 + j] * s;
        }
        Whp[idx] = (_Float16)v;
    } else if (idx < 87104) {
        int i = idx - 81920; int ce = i / 9;
        float s = gg[ce] * rsqrtf(gv[ce] + EPSF);
        ws[WS_WFOLD + i] = gen_w[i] * s;
    } else if (idx < 87680) {
        int ce = idx - 87104;
        float s = gg[ce] * rsqrtf(gv[ce] + EPSF);
        ws[WS_SHIFT + ce] = gb[ce] - gm[ce] * s;
    } else if (idx < 87808) {
        int oup = idx - 87680;
        float s = cg[oup] * rsqrtf(cv[oup] + EPSF);
        ws[WS_BIAS + oup] = cb[oup] - cm[oup] * s;
    }
}

// 2048 blocks: (b, c, quarter). Conv + relu, accumulate sum/sumsq for gates.
__global__ __launch_bounds__(256) void k_stats(
    const float* __restrict__ x, const float* __restrict__ ws,
    float* __restrict__ part)
{
    __shared__ float xs[34 * 132];
    __shared__ __align__(16) float wfl[84];
    __shared__ float shl[9];
    __shared__ float r1[4], r2[4];
    int bid = blockIdx.x; int b = bid >> 8; int c = (bid >> 2) & 63; int q = bid & 3;
    int t = threadIdx.x;
    const float* xp = x + (size_t)(b * C_ + c) * HW_;
    for (int i = t; i < 4420; i += 256) {
        int r = i / 130, cc = i - r * 130;
        int yy = q * 32 + r - 1, xx = cc - 1;
        float v = 0.f;
        if (yy >= 0 && yy < 128 && xx >= 0 && xx < 128) v = xp[yy * 128 + xx];
        xs[r * 132 + cc] = v;
    }
    if (t < 84) wfl[t] = ws[WS_WFOLD + c * 81 + ((t < 81) ? t : 80)];
    if (t >= 84 && t < 93) shl[t - 84] = ws[WS_SHIFT + c * 9 + (t - 84)];
    __syncthreads();

    float wv[84];
#pragma unroll
    for (int i = 0; i < 21; ++i) *(float4*)&wv[i * 4] = *(const float4*)&wfl[i * 4];
    float sh9[9];
#pragma unroll
    for (int i = 0; i < 9; ++i) sh9[i] = shl[i];

    float s1 = 0.f, s2 = 0.f;
    for (int i = 0; i < 16; ++i) {
        int id = i * 256 + t; int row = id >> 7, col = id & 127;
        float nb[9];
#pragma unroll
        for (int dy = 0; dy < 3; ++dy)
#pragma unroll
            for (int dx = 0; dx < 3; ++dx) nb[dy * 3 + dx] = xs[(row + dy) * 132 + col + dx];
        float uv[9];
#pragma unroll
        for (int j = 0; j < 9; ++j) uv[j] = sh9[j];
#pragma unroll
        for (int k = 0; k < 9; ++k) {
            float xv = nb[k];
#pragma unroll
            for (int j = 0; j < 9; ++j) uv[j] = fmaf(wv[j * 9 + k], xv, uv[j]);
        }
#pragma unroll
        for (int j = 0; j < 9; ++j) {
            float v = fmaxf(uv[j], 0.f);
            s1 += v; s2 = fmaf(v, v, s2);
        }
    }
#pragma unroll
    for (int off = 32; off > 0; off >>= 1) {
        s1 += __shfl_down(s1, off, 64);
        s2 += __shfl_down(s2, off, 64);
    }
    int wid = t >> 6;
    if ((t & 63) == 0) { r1[wid] = s1; r2[wid] = s2; }
    __syncthreads();
    if (t == 0) {
        part[bid * 2]     = r1[0] + r1[1] + r1[2] + r1[3];
        part[bid * 2 + 1] = r2[0] + r2[1] + r2[2] + r2[3];
    }
}

__global__ __launch_bounds__(256) void k_gate(
    const float* __restrict__ part,
    const float* __restrict__ cwt, const float* __restrict__ cbs,
    const float* __restrict__ swt, const float* __restrict__ sbs,
    const float* __restrict__ gnw, const float* __restrict__ gnb,
    const float* __restrict__ wadd, float4* __restrict__ gate)
{
    int i = blockIdx.x * 256 + threadIdx.x;
    if (i >= 512) return;
    int b = i >> 6, c = i & 63;
    float s1 = 0.f, s2 = 0.f;
    for (int q = 0; q < 4; ++q) {
        int pi = (b * 256 + c * 4 + q) * 2;
        s1 += part[pi]; s2 += part[pi + 1];
    }
    const float N = 9.f * 16384.f;
    float mean = s1 / N;
    float var = s2 / N - mean * mean;
    float inv = rsqrtf(var + EPSF);
    int cgi = c & 7;
    float wa = wadd[0];
    float cgt = sigmf(cwt[cgi] * mean + cbs[cgi]);
    const float NL2E = -1.44269504f;   // sigm(t)=rcp(1+exp2(-t*log2e))
    float4 o;
    o.x = wa * cgt;
    o.y = 1.f - wa;
    o.z = NL2E * (swt[cgi] * gnw[cgi] * inv);
    o.w = NL2E * (swt[cgi] * (gnb[cgi] - mean * inv * gnw[cgi]) + sbs[cgi]);
    gate[i] = o;
}

// nb*1024 blocks: (bbl, tile-pair p(64), cq(16)). Thread owns 1 px of a 16x16
// region and 4 channels (cq*4..+3); conv+relu+gate -> 2 packed dwords per j
// stored straight into the B-image in MFMA fragment order. High occupancy
// (5.5KB LDS, no MFMA), pure VALU throughput.
__global__ __launch_bounds__(256) void k_apply(
    const float* __restrict__ x, float* __restrict__ ws, int b0)
{
    __shared__ float xs[4][18 * 19];
    int bid = blockIdx.x;
    int cq = bid & 15, p = (bid >> 4) & 63, bbl = bid >> 10;
    int b = b0 + bbl;
    int oh0 = (p >> 3) << 4, ow0 = (p & 7) << 4;
    int t = threadIdx.x;
    int row16 = t >> 4, col = t & 15;

    for (int i = t; i < 1296; i += 256) {
        int ch = i / 324, rr = i - ch * 324;
        int r = rr / 18, cc = rr - r * 18;
        int yy = oh0 + r - 1, xx = ow0 + cc - 1;
        float v = 0.f;
        if (yy >= 0 && yy < 128 && xx >= 0 && xx < 128)
            v = x[(size_t)(b * C_ + cq * 4 + ch) * HW_ + yy * 128 + xx];
        xs[ch][r * 19 + cc] = v;
    }
    __syncthreads();

    float nb4[4][9];
#pragma unroll
    for (int ch = 0; ch < 4; ++ch)
#pragma unroll
        for (int dy = 0; dy < 3; ++dy)
#pragma unroll
            for (int dx = 0; dx < 3; ++dx)
                nb4[ch][dy * 3 + dx] = xs[ch][(row16 + dy) * 19 + col + dx];

    float4 g[4];
#pragma unroll
    for (int ch = 0; ch < 4; ++ch)
        g[ch] = *(const float4*)(ws + WS_GATE + (size_t)(b * C_ + cq * 4 + ch) * 4);

    int tile = ((p >> 3) * 2 + (row16 >> 3)) * 8 + (p & 7);
    int px = (row16 & 7) * 16 + col;
    _Float16* Bimg = (_Float16*)(ws + WS_BIMG)
        + (size_t)(bbl * 128 + tile) * (KB_ * 1024) + (size_t)px * 8;

#pragma unroll 1
    for (int j = 0; j < 9; ++j) {            // <=40 live uniform scalars
        float wj[4][9], sj[4];
#pragma unroll
        for (int ch = 0; ch < 4; ++ch) {
            const float* wp = ws + WS_WFOLD + (cq * 4 + ch) * 81 + j * 9;
#pragma unroll
            for (int k = 0; k < 9; ++k) wj[ch][k] = wp[k];
            sj[ch] = ws[WS_SHIFT + (cq * 4 + ch) * 9 + j];
        }
        float uv[4];
#pragma unroll
        for (int ch = 0; ch < 4; ++ch) {
            float a = sj[ch];
#pragma unroll
            for (int k = 0; k < 9; ++k) a = fmaf(wj[ch][k], nb4[ch][k], a);
            float v = fmaxf(a, 0.f);
            float e = __builtin_amdgcn_exp2f(fmaf(g[ch].z, v, g[ch].w));
            uv[ch] = v * fmaf(g[ch].y, __builtin_amdgcn_rcpf(1.f + e), g[ch].x);
        }
        union { fp16x2 p2[2]; uint2 u; } pk;
        pk.p2[0] = __builtin_amdgcn_cvt_pkrtz(uv[0], uv[1]);
        pk.p2[1] = __builtin_amdgcn_cvt_pkrtz(uv[2], uv[3]);
        *(uint2*)(Bimg + (size_t)(cq * 5 + (j >> 1)) * 1024 + (j & 1) * 4) = pk.u;
    }
    // zero the 4 pad slots (vv 36..39) so MFMA sees clean zeros every run
    uint2 z; z.x = 0u; z.y = 0u;
    *(uint2*)(Bimg + (size_t)(cq * 5 + 4) * 1024 + 4) = z;
}

// nb*128 blocks: (bbl, tile). Pure streaming GEMM: 128oup x 128px, K=640.
// A,B fragments straight from global (coalesced 16B/lane), no loop barriers.
__global__ __launch_bounds__(256) void k_main(
    const float* __restrict__ ws, float* __restrict__ out, int b0)
{
    __shared__ float bias_s[128];
    int t = threadIdx.x;
    int bid = blockIdx.x;
    int bbl = bid >> 7, tile = bid & 127;
    int b = b0 + bbl;
    int oh0 = (tile >> 3) << 3, ow0 = (tile & 7) << 4;
    if (t < 128) bias_s[t] = ws[WS_BIAS + t];
    __syncthreads();

    int w = __builtin_amdgcn_readfirstlane(t >> 6);
    int lane = t & 63, quad = lane >> 4, l15 = lane & 15;
    int arow = ((w & 1) << 6) + l15;       // oup rows
    int brow = ((w >> 1) << 6) + l15;      // px rows

    const _Float16* Aq = (const _Float16*)(ws + WS_WH)
        + (size_t)quad * 1024 + (size_t)arow * 8;
    const _Float16* Bq = (const _Float16*)(ws + WS_BIMG)
        + (size_t)(bbl * 128 + tile) * (KB_ * 1024)
        + (size_t)quad * 1024 + (size_t)brow * 8;

    v4f acc[4][4];
#pragma unroll
    for (int a = 0; a < 4; ++a)
#pragma unroll
        for (int bb = 0; bb < 4; ++bb) acc[a][bb] = (v4f)0.f;

#pragma unroll 1
    for (int it = 0; it < 10; ++it) {
        size_t ito = (size_t)it * 8192;
#pragma unroll
        for (int ks = 0; ks < 2; ++ks) {
            v8h A[4], Bf[4];
#pragma unroll
            for (int a = 0; a < 4; ++a)
                A[a] = *(const v8h*)(Aq + ito + ks * 4096 + a * 128);
#pragma unroll
            for (int bb = 0; bb < 4; ++bb)
                Bf[bb] = *(const v8h*)(Bq + ito + ks * 4096 + bb * 128);
#pragma unroll
            for (int a = 0; a < 4; ++a)
#pragma unroll
                for (int bb = 0; bb < 4; ++bb)
                    acc[a][bb] = __builtin_amdgcn_mfma_f32_16x16x32_f16(A[a], Bf[bb], acc[a][bb], 0, 0, 0);
        }
    }

    // epilogue: bias + SiLU; C/D layout col=lane&15(px), row=quad*4+reg(oup)
    size_t ob = (size_t)b * 128 * HW_;
#pragma unroll
    for (int a = 0; a < 4; ++a) {
#pragma unroll
        for (int r = 0; r < 4; ++r) {
            int oup = ((w & 1) << 6) + (a << 4) + (quad << 2) + r;
            float bo = bias_s[oup];
#pragma unroll
            for (int bb = 0; bb < 4; ++bb) {
                int p2 = ((w >> 1) << 6) + (bb << 4) + l15;
                int py2 = p2 >> 4, px2 = p2 & 15;
                float z = acc[a][bb][r] + bo;
                out[ob + (size_t)oup * HW_ + (oh0 + py2) * W_ + ow0 + px2] = z * sigmf(z);
            }
        }
    }
}

extern "C" void kernel_launch(void* const* d_in, const int* in_sizes, int n_in,
                              void* d_out, int out_size, void* d_ws, size_t ws_size,
                              hipStream_t stream)
{
    const float* x      = (const float*)d_in[0];
    const float* gen_w  = (const float*)d_in[1];
    const float* gg     = (const float*)d_in[2];
    const float* gb     = (const float*)d_in[3];
    const float* gm     = (const float*)d_in[4];
    const float* gv     = (const float*)d_in[5];
    const float* gnw    = (const float*)d_in[6];
    const float* gnb    = (const float*)d_in[7];
    const float* cwt    = (const float*)d_in[8];
    const float* cbs    = (const float*)d_in[9];
    const float* swt    = (const float*)d_in[10];
    const float* sbs    = (const float*)d_in[11];
    const float* wadd   = (const float*)d_in[12];
    const float* conv_w = (const float*)d_in[13];
    const float* cg2    = (const float*)d_in[14];
    const float* cb2    = (const float*)d_in[15];
    const float* cm2    = (const float*)d_in[16];
    const float* cv2    = (const float*)d_in[17];
    float* ws  = (float*)d_ws;
    float* out = (float*)d_out;

    // pick the largest batch chunk whose B-image fits in ws
    size_t avail = ws_size / 4;   // floats
    int nb = 1;
    const int cands[4] = {8, 4, 2, 1};
    for (int i = 0; i < 4; ++i) {
        if ((size_t)WS_BIMG + (size_t)cands[i] * BIMG_BATCH_FLT <= avail) { nb = cands[i]; break; }
    }

    k_fold<<<343, 256, 0, stream>>>(gen_w, gg, gb, gm, gv, conv_w, cg2, cb2, cm2, cv2, ws);
    k_stats<<<2048, 256, 0, stream>>>(x, ws, ws + WS_PART);
    k_gate<<<2, 256, 0, stream>>>(ws + WS_PART, cwt, cbs, swt, sbs, gnw, gnb, wadd,
                                  (float4*)(ws + WS_GATE));
    for (int b0 = 0; b0 < 8; b0 += nb) {
        k_apply<<<nb * 1024, 256, 0, stream>>>(x, ws, b0);
        k_main<<<nb * 128, 256, 0, stream>>>(ws, out, b0);
    }
}

// Round 4
// 282.675 us; speedup vs baseline: 1.0676x; 1.0676x over previous
//
#include <hip/hip_runtime.h>
#include <math.h>

// SIFA fused, MFMA v6b (v6 + compile fix: named bit-cast instead of anonymous
// union compound literal, which C++ rejects).
// v5 regressed: k_apply's 8B half-dense stores (2x write amplification,
// 1.6TB/s) + k_stats (~100us) still duplicating the conv. v6: conv computed
// ONCE in k_conv -> pre-gate f16 B-image with DENSE 16B stores (per-thread
// LDS row staging to merge j-pairs into full cells) + in-kernel stats
// partials (k_stats deleted). k_gate reduces partials. k_gapply applies the
// gate in-place on the L3-resident B-image (gate params block-uniform per
// kb). k_main: streaming GEMM with explicit 2-deep B pipeline, VGPR<=128.

#define EPSF 1e-5f
typedef _Float16 v8h __attribute__((ext_vector_type(8)));
typedef __fp16 fp16x2 __attribute__((ext_vector_type(2)));   // cvt_pkrtz native type
typedef float v4f __attribute__((ext_vector_type(4)));

static constexpr int C_ = 64, HW_ = 16384, W_ = 128;
static constexpr int KB_ = 80;                 // K = 640 = 80 cells of 8 f16

// ws float offsets
static constexpr int WS_WFOLD = 0;       // 5184: [c][j][k] folded depthwise weights
static constexpr int WS_SHIFT = 5184;    // 576
static constexpr int WS_BIAS  = 5760;    // 128
static constexpr int WS_GATE  = 5888;    // 512*4 {wa*cgate, 1-wa, -log2e*a_sp, -log2e*b_sp}
static constexpr int WS_PART  = 7936;    // 8b*16cq*8(ch*2+s)*64p = 65536
static constexpr int WS_WH    = 73472;   // 80*128*8 f16 = 40960 floats: Wh[kb][oup][8]
static constexpr int WS_BIMG  = 114688;  // B-image: per batch 128tile*80kb*128px*8 f16
static constexpr size_t BIMG_BATCH_F16 = (size_t)128 * KB_ * 128 * 8;   // 10,485,760
static constexpr size_t BIMG_BATCH_FLT = BIMG_BATCH_F16 / 2;            // 5,242,880

__device__ __forceinline__ float sigmf(float v) { return 1.f / (1.f + __expf(-v)); }

__device__ __forceinline__ unsigned int pk_u32(float a, float b) {
    fp16x2 h = __builtin_amdgcn_cvt_pkrtz(a, b);
    return __builtin_bit_cast(unsigned int, h);
}

// K-slot map: k = grp*80 + tp*40 + vv; grp=c>>3, tp=(c>>2)&1, vv=j*4+(c&3)
// (vv 36..39 zero pads). Cell kb=k>>3 has block-constant channel quad
// cbase = grp*8+tp*4, element e: c = cbase+(e&3), j = 2*(kb%5)+(e>>2).
__global__ __launch_bounds__(256) void k_fold(
    const float* __restrict__ gen_w,
    const float* __restrict__ gg, const float* __restrict__ gb,
    const float* __restrict__ gm, const float* __restrict__ gv,
    const float* __restrict__ conv_w,
    const float* __restrict__ cg, const float* __restrict__ cb,
    const float* __restrict__ cm, const float* __restrict__ cv,
    float* __restrict__ ws)
{
    int idx = blockIdx.x * 256 + threadIdx.x;
    _Float16* Whp = (_Float16*)(ws + WS_WH);
    if (idx < 81920) {
        // fragment layout: idx = (kb*128 + oup)*8 + e; K index k = kb*8+e
        int kb = idx >> 10, oup = (idx >> 3) & 127, e = idx & 7;
        int k = kb * 8 + e;
        int grp = k / 80, rr = k - grp * 80;
        int tp = rr / 40, vv = rr - tp * 40;
        float v = 0.f;
        if (vv < 36) {
            int j = vv >> 2, cl = vv & 3, c = grp * 8 + tp * 4 + cl;
            float s = cg[oup] * rsqrtf(cv[oup] + EPSF);
            v = conv_w[(oup * C_ + c) * 9 + j] * s;
        }
        Whp[idx] = (_Float16)v;
    } else if (idx < 87104) {
        int i = idx - 81920; int ce = i / 9;
        float s = gg[ce] * rsqrtf(gv[ce] + EPSF);
        ws[WS_WFOLD + i] = gen_w[i] * s;
    } else if (idx < 87680) {
        int ce = idx - 87104;
        float s = gg[ce] * rsqrtf(gv[ce] + EPSF);
        ws[WS_SHIFT + ce] = gb[ce] - gm[ce] * s;
    } else if (idx < 87808) {
        int oup = idx - 87680;
        float s = cg[oup] * rsqrtf(cv[oup] + EPSF);
        ws[WS_BIAS + oup] = cb[oup] - cm[oup] * s;
    }
}

// nb*1024 blocks: (bbl, p(64), cq(16)). Thread owns 1 px of a 16x16 region,
// 4 channels. Conv+relu ONCE; pre-gate u staged per-thread in LDS row, then
// 5 dense 16B stores into the B-image; block-reduced sum/sumsq partials.
__global__ __launch_bounds__(256) void k_conv(
    const float* __restrict__ x, float* __restrict__ ws, int b0)
{
    __shared__ float xs[4][18 * 19];
    __shared__ unsigned int ul[256 * 22];   // per-thread 22-dword row (8B aligned cells)
    __shared__ float red[4][8];
    int bid = blockIdx.x;
    int cq = bid & 15, p = (bid >> 4) & 63, bbl = bid >> 10;
    int b = b0 + bbl;
    int oh0 = (p >> 3) << 4, ow0 = (p & 7) << 4;
    int t = threadIdx.x;
    int row16 = t >> 4, col = t & 15;

    for (int i = t; i < 1296; i += 256) {
        int ch = i / 324, rr = i - ch * 324;
        int r = rr / 18, cc = rr - r * 18;
        int yy = oh0 + r - 1, xx = ow0 + cc - 1;
        float v = 0.f;
        if (yy >= 0 && yy < 128 && xx >= 0 && xx < 128)
            v = x[(size_t)(b * C_ + cq * 4 + ch) * HW_ + yy * 128 + xx];
        xs[ch][r * 19 + cc] = v;
    }
    __syncthreads();

    float nb4[4][9];
#pragma unroll
    for (int ch = 0; ch < 4; ++ch)
#pragma unroll
        for (int dy = 0; dy < 3; ++dy)
#pragma unroll
            for (int dx = 0; dx < 3; ++dx)
                nb4[ch][dy * 3 + dx] = xs[ch][(row16 + dy) * 19 + col + dx];

    float st[8];                              // st[ch*2] = sum, st[ch*2+1] = sumsq
#pragma unroll
    for (int k = 0; k < 8; ++k) st[k] = 0.f;

#pragma unroll 1
    for (int j = 0; j < 9; ++j) {             // <=40 live uniform scalars (proven OK)
        float wj[4][9], sj[4];
#pragma unroll
        for (int ch = 0; ch < 4; ++ch) {
            const float* wp = ws + WS_WFOLD + (cq * 4 + ch) * 81 + j * 9;
#pragma unroll
            for (int k = 0; k < 9; ++k) wj[ch][k] = wp[k];
            sj[ch] = ws[WS_SHIFT + (cq * 4 + ch) * 9 + j];
        }
        float uv[4];
#pragma unroll
        for (int ch = 0; ch < 4; ++ch) {
            float a = sj[ch];
#pragma unroll
            for (int k = 0; k < 9; ++k) a = fmaf(wj[ch][k], nb4[ch][k], a);
            float v = fmaxf(a, 0.f);
            uv[ch] = v;
            st[ch * 2] += v;
            st[ch * 2 + 1] = fmaf(v, v, st[ch * 2 + 1]);
        }
        uint2 pk;
        pk.x = pk_u32(uv[0], uv[1]);
        pk.y = pk_u32(uv[2], uv[3]);
        int ci = j >> 1;
        *(uint2*)&ul[t * 22 + ci * 4 + (j & 1) * 2] = pk;
    }
    {   // pads of cell 4 (e4..7 = vv 36..39) are zeros
        uint2 z; z.x = 0u; z.y = 0u;
        *(uint2*)&ul[t * 22 + 18] = z;
    }

    // ---- dense 16B stores: 5 cells per thread, lane stride 16B (perfect)
    int tile = ((p >> 3) * 2 + (row16 >> 3)) * 8 + (p & 7);
    int px = (row16 & 7) * 16 + col;
    int kbBase = (cq >> 1) * 10 + (cq & 1) * 5;
    _Float16* Bimg = (_Float16*)(ws + WS_BIMG) + (size_t)bbl * BIMG_BATCH_F16;
#pragma unroll
    for (int ci = 0; ci < 5; ++ci) {
        uint2 lo = *(uint2*)&ul[t * 22 + ci * 4];
        uint2 hi = *(uint2*)&ul[t * 22 + ci * 4 + 2];
        uint4 cell; cell.x = lo.x; cell.y = lo.y; cell.z = hi.x; cell.w = hi.y;
        *(uint4*)(Bimg + (size_t)(tile * KB_ + kbBase + ci) * 1024 + (size_t)px * 8) = cell;
    }

    // ---- stats: wave shuffle reduce, then cross-wave via tiny LDS
#pragma unroll
    for (int off = 32; off > 0; off >>= 1)
#pragma unroll
        for (int k = 0; k < 8; ++k) st[k] += __shfl_down(st[k], off, 64);
    int w = t >> 6, lane = t & 63;
    if (lane == 0)
#pragma unroll
        for (int k = 0; k < 8; ++k) red[w][k] = st[k];
    __syncthreads();
    if (t < 8) {
        float v = red[0][t] + red[1][t] + red[2][t] + red[3][t];
        float* part = ws + WS_PART;
        part[(size_t)((b * 16 + cq) * 8 + t) * 64 + p] = v;
    }
}

__global__ __launch_bounds__(256) void k_gate(
    const float* __restrict__ part,
    const float* __restrict__ cwt, const float* __restrict__ cbs,
    const float* __restrict__ swt, const float* __restrict__ sbs,
    const float* __restrict__ gnw, const float* __restrict__ gnb,
    const float* __restrict__ wadd, float4* __restrict__ gate, int b0, int nb)
{
    int i = blockIdx.x * 256 + threadIdx.x;
    if (i >= nb * 64) return;
    int b = b0 + (i >> 6), c = i & 63;
    const float* pp = part + (size_t)((b * 16 + (c >> 2)) * 8 + (c & 3) * 2) * 64;
    float s1 = 0.f, s2 = 0.f;
#pragma unroll
    for (int q = 0; q < 16; ++q) {
        float4 a = *(const float4*)(pp + q * 4);
        float4 d = *(const float4*)(pp + 64 + q * 4);
        s1 += a.x + a.y + a.z + a.w;
        s2 += d.x + d.y + d.z + d.w;
    }
    const float N = 9.f * 16384.f;
    float mean = s1 / N;
    float var = s2 / N - mean * mean;
    float inv = rsqrtf(var + EPSF);
    int cgi = c & 7;
    float wa = wadd[0];
    float cgt = sigmf(cwt[cgi] * mean + cbs[cgi]);
    const float NL2E = -1.44269504f;   // sigm(t)=rcp(1+exp2(-t*log2e))
    float4 o;
    o.x = wa * cgt;
    o.y = 1.f - wa;
    o.z = NL2E * (swt[cgi] * gnw[cgi] * inv);
    o.w = NL2E * (swt[cgi] * (gnb[cgi] - mean * inv * gnw[cgi]) + sbs[cgi]);
    gate[b * 64 + c] = o;
}

// grid (160, nb): (kb*2+half, bbl). Gate applied in-place on the B-image.
// Gate params are block-uniform (channel quad determined by kb alone).
__global__ __launch_bounds__(256) void k_gapply(float* __restrict__ ws, int b0)
{
    int kb = blockIdx.x >> 1, h = blockIdx.x & 1, bbl = blockIdx.y;
    int b = b0 + bbl;
    int grp = kb / 10, r = kb - grp * 10, tp = r / 5;
    int cbase = grp * 8 + tp * 4;
    const float4* gp = (const float4*)(ws + WS_GATE);
    float4 g0 = gp[b * 64 + cbase];
    float4 g1 = gp[b * 64 + cbase + 1];
    float4 g2 = gp[b * 64 + cbase + 2];
    float4 g3 = gp[b * 64 + cbase + 3];
    _Float16* base = (_Float16*)(ws + WS_BIMG) + (size_t)bbl * BIMG_BATCH_F16
                   + (size_t)kb * 1024;
    int t = threadIdx.x;
    int tsub = t >> 7;                 // which tile of the pair
    int off = (t & 127) * 8;
#pragma unroll 1
    for (int i = 0; i < 32; ++i) {
        int tl = h * 64 + i * 2 + tsub;
        _Float16* p = base + (size_t)tl * (KB_ * 1024) + off;
        v8h v = *(const v8h*)p;
        float u[8];
#pragma unroll
        for (int e = 0; e < 8; ++e) {
            float f = (float)v[e];
            float4 g = (e & 3) == 0 ? g0 : ((e & 3) == 1 ? g1 : ((e & 3) == 2 ? g2 : g3));
            float ex = __builtin_amdgcn_exp2f(fmaf(g.z, f, g.w));
            u[e] = f * fmaf(g.y, __builtin_amdgcn_rcpf(1.f + ex), g.x);
        }
        uint2 lo, hi;
        lo.x = pk_u32(u[0], u[1]);
        lo.y = pk_u32(u[2], u[3]);
        hi.x = pk_u32(u[4], u[5]);
        hi.y = pk_u32(u[6], u[7]);
        uint4 cell; cell.x = lo.x; cell.y = lo.y; cell.z = hi.x; cell.w = hi.y;
        *(uint4*)p = cell;
    }
}

// nb*128 blocks: (bbl, tile). Pure streaming GEMM: 128oup x 128px, K=640.
// 2-deep B-fragment pipeline (named sets, static indexing); A from L2.
__global__ __launch_bounds__(256, 4) void k_main(
    const float* __restrict__ ws, float* __restrict__ out, int b0)
{
    __shared__ float bias_s[128];
    int t = threadIdx.x;
    int bid = blockIdx.x;
    int bbl = bid >> 7, tile = bid & 127;
    int b = b0 + bbl;
    int oh0 = (tile >> 3) << 3, ow0 = (tile & 7) << 4;
    if (t < 128) bias_s[t] = ws[WS_BIAS + t];
    __syncthreads();

    int w = __builtin_amdgcn_readfirstlane(t >> 6);
    int lane = t & 63, quad = lane >> 4, l15 = lane & 15;
    int arow = ((w & 1) << 6) + l15;       // oup rows
    int brow = ((w >> 1) << 6) + l15;      // px rows

    const _Float16* Aq = (const _Float16*)(ws + WS_WH)
        + (size_t)quad * 1024 + (size_t)arow * 8;
    const _Float16* Bq = (const _Float16*)(ws + WS_BIMG)
        + (size_t)bbl * BIMG_BATCH_F16 + (size_t)tile * (KB_ * 1024)
        + (size_t)quad * 1024 + (size_t)brow * 8;

    v4f acc[4][4];
#pragma unroll
    for (int a = 0; a < 4; ++a)
#pragma unroll
        for (int bb = 0; bb < 4; ++bb) acc[a][bb] = (v4f)0.f;

    v8h A[4], B0[4], B1[4];
    auto LDA = [&](int s) {
        size_t o = (size_t)s << 12;
#pragma unroll
        for (int a = 0; a < 4; ++a) A[a] = *(const v8h*)(Aq + o + a * 128);
    };
    auto LDB = [&](int s, v8h* B) {
        size_t o = (size_t)s << 12;
#pragma unroll
        for (int bb = 0; bb < 4; ++bb) B[bb] = *(const v8h*)(Bq + o + bb * 128);
    };
    auto MM = [&](v8h* B) {
#pragma unroll
        for (int a = 0; a < 4; ++a)
#pragma unroll
            for (int bb = 0; bb < 4; ++bb)
                acc[a][bb] = __builtin_amdgcn_mfma_f32_16x16x32_f16(A[a], B[bb], acc[a][bb], 0, 0, 0);
    };

    LDB(0, B0);
#pragma unroll 1
    for (int s = 0; s < 18; s += 2) {
        LDB(s + 1, B1);
        LDA(s);
        MM(B0);
        LDB(s + 2, B0);
        LDA(s + 1);
        MM(B1);
    }
    LDB(19, B1);
    LDA(18); MM(B0);
    LDA(19); MM(B1);

    // epilogue: bias + SiLU; C/D layout col=lane&15(px), row=quad*4+reg(oup)
    size_t ob = (size_t)b * 128 * HW_;
#pragma unroll
    for (int a = 0; a < 4; ++a) {
#pragma unroll
        for (int r = 0; r < 4; ++r) {
            int oup = ((w & 1) << 6) + (a << 4) + (quad << 2) + r;
            float bo = bias_s[oup];
#pragma unroll
            for (int bb = 0; bb < 4; ++bb) {
                int p2 = ((w >> 1) << 6) + (bb << 4) + l15;
                int py2 = p2 >> 4, px2 = p2 & 15;
                float z = acc[a][bb][r] + bo;
                out[ob + (size_t)oup * HW_ + (oh0 + py2) * W_ + ow0 + px2] = z * sigmf(z);
            }
        }
    }
}

extern "C" void kernel_launch(void* const* d_in, const int* in_sizes, int n_in,
                              void* d_out, int out_size, void* d_ws, size_t ws_size,
                              hipStream_t stream)
{
    const float* x      = (const float*)d_in[0];
    const float* gen_w  = (const float*)d_in[1];
    const float* gg     = (const float*)d_in[2];
    const float* gb     = (const float*)d_in[3];
    const float* gm     = (const float*)d_in[4];
    const float* gv     = (const float*)d_in[5];
    const float* gnw    = (const float*)d_in[6];
    const float* gnb    = (const float*)d_in[7];
    const float* cwt    = (const float*)d_in[8];
    const float* cbs    = (const float*)d_in[9];
    const float* swt    = (const float*)d_in[10];
    const float* sbs    = (const float*)d_in[11];
    const float* wadd   = (const float*)d_in[12];
    const float* conv_w = (const float*)d_in[13];
    const float* cg2    = (const float*)d_in[14];
    const float* cb2    = (const float*)d_in[15];
    const float* cm2    = (const float*)d_in[16];
    const float* cv2    = (const float*)d_in[17];
    float* ws  = (float*)d_ws;
    float* out = (float*)d_out;

    // pick the largest batch chunk whose B-image fits in ws
    size_t avail = ws_size / 4;   // floats
    int nb = 1;
    const int cands[4] = {8, 4, 2, 1};
    for (int i = 0; i < 4; ++i) {
        if ((size_t)WS_BIMG + (size_t)cands[i] * BIMG_BATCH_FLT <= avail) { nb = cands[i]; break; }
    }

    k_fold<<<343, 256, 0, stream>>>(gen_w, gg, gb, gm, gv, conv_w, cg2, cb2, cm2, cv2, ws);
    for (int b0 = 0; b0 < 8; b0 += nb) {
        k_conv<<<nb * 1024, 256, 0, stream>>>(x, ws, b0);
        k_gate<<<(nb * 64 + 255) / 256, 256, 0, stream>>>(
            ws + WS_PART, cwt, cbs, swt, sbs, gnw, gnb, wadd,
            (float4*)(ws + WS_GATE), b0, nb);
        k_gapply<<<dim3(160, nb), 256, 0, stream>>>(ws, b0);
        k_main<<<nb * 128, 256, 0, stream>>>(ws, out, b0);
    }
}

// Round 5
// 236.690 us; speedup vs baseline: 1.2750x; 1.1943x over previous
//
#include <hip/hip_runtime.h>
#include <math.h>

// SIFA fused, MFMA v7.
// v6 passed (282.7) but the 160MB B-image made 3 global trips (W pre-gate,
// R+W gapply, R main) ~= 640MB intermediate traffic + an extra pass.
// v7 deletes k_gapply: gate is fused into k_main's STAGING phase (not the
// MFMA loop): N=64px blocks, kb-major LDS tile Bs[40][64][8] (40KB, K split
// in 2 rounds). Each gated element hits LDS once, is consumed by all 4
// waves; staging global loads are 1KB/wave coalesced; kb-major layout makes
// LDS writes/reads contiguous-256B (conflict-free, no swizzle). B-image is
// now write-once/read-once. k_conv/k_fold/k_gate byte-identical to v6.

#define EPSF 1e-5f
typedef _Float16 v8h __attribute__((ext_vector_type(8)));
typedef __fp16 fp16x2 __attribute__((ext_vector_type(2)));   // cvt_pkrtz native type
typedef float v4f __attribute__((ext_vector_type(4)));

static constexpr int C_ = 64, HW_ = 16384, W_ = 128;
static constexpr int KB_ = 80;                 // K = 640 = 80 cells of 8 f16

// ws float offsets
static constexpr int WS_WFOLD = 0;       // 5184: [c][j][k] folded depthwise weights
static constexpr int WS_SHIFT = 5184;    // 576
static constexpr int WS_BIAS  = 5760;    // 128
static constexpr int WS_GATE  = 5888;    // 512*4 {wa*cgate, 1-wa, -log2e*a_sp, -log2e*b_sp}
static constexpr int WS_PART  = 7936;    // 8b*16cq*8(ch*2+s)*64p = 65536
static constexpr int WS_WH    = 73472;   // 80*128*8 f16 = 40960 floats: Wh[kb][oup][8]
static constexpr int WS_BIMG  = 114688;  // B-image: per batch 128tile*80kb*128px*8 f16
static constexpr size_t BIMG_BATCH_F16 = (size_t)128 * KB_ * 128 * 8;   // 10,485,760
static constexpr size_t BIMG_BATCH_FLT = BIMG_BATCH_F16 / 2;            // 5,242,880

__device__ __forceinline__ float sigmf(float v) { return 1.f / (1.f + __expf(-v)); }

__device__ __forceinline__ unsigned int pk_u32(float a, float b) {
    fp16x2 h = __builtin_amdgcn_cvt_pkrtz(a, b);
    return __builtin_bit_cast(unsigned int, h);
}

// K-slot map: k = grp*80 + tp*40 + vv; grp=c>>3, tp=(c>>2)&1, vv=j*4+(c&3)
// (vv 36..39 zero pads). Cell kb=k>>3 has block-constant channel quad
// cbase = grp*8+tp*4, element e: c = cbase+(e&3), j = 2*(kb%5)+(e>>2).
__global__ __launch_bounds__(256) void k_fold(
    const float* __restrict__ gen_w,
    const float* __restrict__ gg, const float* __restrict__ gb,
    const float* __restrict__ gm, const float* __restrict__ gv,
    const float* __restrict__ conv_w,
    const float* __restrict__ cg, const float* __restrict__ cb,
    const float* __restrict__ cm, const float* __restrict__ cv,
    float* __restrict__ ws)
{
    int idx = blockIdx.x * 256 + threadIdx.x;
    _Float16* Whp = (_Float16*)(ws + WS_WH);
    if (idx < 81920) {
        // fragment layout: idx = (kb*128 + oup)*8 + e; K index k = kb*8+e
        int kb = idx >> 10, oup = (idx >> 3) & 127, e = idx & 7;
        int k = kb * 8 + e;
        int grp = k / 80, rr = k - grp * 80;
        int tp = rr / 40, vv = rr - tp * 40;
        float v = 0.f;
        if (vv < 36) {
            int j = vv >> 2, cl = vv & 3, c = grp * 8 + tp * 4 + cl;
            float s = cg[oup] * rsqrtf(cv[oup] + EPSF);
            v = conv_w[(oup * C_ + c) * 9 + j] * s;
        }
        Whp[idx] = (_Float16)v;
    } else if (idx < 87104) {
        int i = idx - 81920; int ce = i / 9;
        float s = gg[ce] * rsqrtf(gv[ce] + EPSF);
        ws[WS_WFOLD + i] = gen_w[i] * s;
    } else if (idx < 87680) {
        int ce = idx - 87104;
        float s = gg[ce] * rsqrtf(gv[ce] + EPSF);
        ws[WS_SHIFT + ce] = gb[ce] - gm[ce] * s;
    } else if (idx < 87808) {
        int oup = idx - 87680;
        float s = cg[oup] * rsqrtf(cv[oup] + EPSF);
        ws[WS_BIAS + oup] = cb[oup] - cm[oup] * s;
    }
}

// nb*1024 blocks: (bbl, p(64), cq(16)). Thread owns 1 px of a 16x16 region,
// 4 channels. Conv+relu ONCE; pre-gate u staged per-thread in LDS row, then
// 5 dense 16B stores into the B-image; block-reduced sum/sumsq partials.
__global__ __launch_bounds__(256) void k_conv(
    const float* __restrict__ x, float* __restrict__ ws, int b0)
{
    __shared__ float xs[4][18 * 19];
    __shared__ unsigned int ul[256 * 22];   // per-thread 22-dword row (8B aligned cells)
    __shared__ float red[4][8];
    int bid = blockIdx.x;
    int cq = bid & 15, p = (bid >> 4) & 63, bbl = bid >> 10;
    int b = b0 + bbl;
    int oh0 = (p >> 3) << 4, ow0 = (p & 7) << 4;
    int t = threadIdx.x;
    int row16 = t >> 4, col = t & 15;

    for (int i = t; i < 1296; i += 256) {
        int ch = i / 324, rr = i - ch * 324;
        int r = rr / 18, cc = rr - r * 18;
        int yy = oh0 + r - 1, xx = ow0 + cc - 1;
        float v = 0.f;
        if (yy >= 0 && yy < 128 && xx >= 0 && xx < 128)
            v = x[(size_t)(b * C_ + cq * 4 + ch) * HW_ + yy * 128 + xx];
        xs[ch][r * 19 + cc] = v;
    }
    __syncthreads();

    float nb4[4][9];
#pragma unroll
    for (int ch = 0; ch < 4; ++ch)
#pragma unroll
        for (int dy = 0; dy < 3; ++dy)
#pragma unroll
            for (int dx = 0; dx < 3; ++dx)
                nb4[ch][dy * 3 + dx] = xs[ch][(row16 + dy) * 19 + col + dx];

    float st[8];                              // st[ch*2] = sum, st[ch*2+1] = sumsq
#pragma unroll
    for (int k = 0; k < 8; ++k) st[k] = 0.f;

#pragma unroll 1
    for (int j = 0; j < 9; ++j) {             // <=40 live uniform scalars (proven OK)
        float wj[4][9], sj[4];
#pragma unroll
        for (int ch = 0; ch < 4; ++ch) {
            const float* wp = ws + WS_WFOLD + (cq * 4 + ch) * 81 + j * 9;
#pragma unroll
            for (int k = 0; k < 9; ++k) wj[ch][k] = wp[k];
            sj[ch] = ws[WS_SHIFT + (cq * 4 + ch) * 9 + j];
        }
        float uv[4];
#pragma unroll
        for (int ch = 0; ch < 4; ++ch) {
            float a = sj[ch];
#pragma unroll
            for (int k = 0; k < 9; ++k) a = fmaf(wj[ch][k], nb4[ch][k], a);
            float v = fmaxf(a, 0.f);
            uv[ch] = v;
            st[ch * 2] += v;
            st[ch * 2 + 1] = fmaf(v, v, st[ch * 2 + 1]);
        }
        uint2 pk;
        pk.x = pk_u32(uv[0], uv[1]);
        pk.y = pk_u32(uv[2], uv[3]);
        int ci = j >> 1;
        *(uint2*)&ul[t * 22 + ci * 4 + (j & 1) * 2] = pk;
    }
    {   // pads of cell 4 (e4..7 = vv 36..39) are zeros
        uint2 z; z.x = 0u; z.y = 0u;
        *(uint2*)&ul[t * 22 + 18] = z;
    }

    // ---- dense 16B stores: 5 cells per thread, lane stride 16B (perfect)
    int tile = ((p >> 3) * 2 + (row16 >> 3)) * 8 + (p & 7);
    int px = (row16 & 7) * 16 + col;
    int kbBase = (cq >> 1) * 10 + (cq & 1) * 5;
    _Float16* Bimg = (_Float16*)(ws + WS_BIMG) + (size_t)bbl * BIMG_BATCH_F16;
#pragma unroll
    for (int ci = 0; ci < 5; ++ci) {
        uint2 lo = *(uint2*)&ul[t * 22 + ci * 4];
        uint2 hi = *(uint2*)&ul[t * 22 + ci * 4 + 2];
        uint4 cell; cell.x = lo.x; cell.y = lo.y; cell.z = hi.x; cell.w = hi.y;
        *(uint4*)(Bimg + (size_t)(tile * KB_ + kbBase + ci) * 1024 + (size_t)px * 8) = cell;
    }

    // ---- stats: wave shuffle reduce, then cross-wave via tiny LDS
#pragma unroll
    for (int off = 32; off > 0; off >>= 1)
#pragma unroll
        for (int k = 0; k < 8; ++k) st[k] += __shfl_down(st[k], off, 64);
    int w = t >> 6, lane = t & 63;
    if (lane == 0)
#pragma unroll
        for (int k = 0; k < 8; ++k) red[w][k] = st[k];
    __syncthreads();
    if (t < 8) {
        float v = red[0][t] + red[1][t] + red[2][t] + red[3][t];
        float* part = ws + WS_PART;
        part[(size_t)((b * 16 + cq) * 8 + t) * 64 + p] = v;
    }
}

__global__ __launch_bounds__(256) void k_gate(
    const float* __restrict__ part,
    const float* __restrict__ cwt, const float* __restrict__ cbs,
    const float* __restrict__ swt, const float* __restrict__ sbs,
    const float* __restrict__ gnw, const float* __restrict__ gnb,
    const float* __restrict__ wadd, float4* __restrict__ gate, int b0, int nb)
{
    int i = blockIdx.x * 256 + threadIdx.x;
    if (i >= nb * 64) return;
    int b = b0 + (i >> 6), c = i & 63;
    const float* pp = part + (size_t)((b * 16 + (c >> 2)) * 8 + (c & 3) * 2) * 64;
    float s1 = 0.f, s2 = 0.f;
#pragma unroll
    for (int q = 0; q < 16; ++q) {
        float4 a = *(const float4*)(pp + q * 4);
        float4 d = *(const float4*)(pp + 64 + q * 4);
        s1 += a.x + a.y + a.z + a.w;
        s2 += d.x + d.y + d.z + d.w;
    }
    const float N = 9.f * 16384.f;
    float mean = s1 / N;
    float var = s2 / N - mean * mean;
    float inv = rsqrtf(var + EPSF);
    int cgi = c & 7;
    float wa = wadd[0];
    float cgt = sigmf(cwt[cgi] * mean + cbs[cgi]);
    const float NL2E = -1.44269504f;   // sigm(t)=rcp(1+exp2(-t*log2e))
    float4 o;
    o.x = wa * cgt;
    o.y = 1.f - wa;
    o.z = NL2E * (swt[cgi] * gnw[cgi] * inv);
    o.w = NL2E * (swt[cgi] * (gnb[cgi] - mean * inv * gnw[cgi]) + sbs[cgi]);
    gate[b * 64 + c] = o;
}

// nb*256 blocks: (bbl, tile, half). M=128 oup x N=64 px, K=640 in 2 rounds of
// 40 cells. Staging phase gates the pre-gate B-image into kb-major LDS
// Bs[40][64][8] (40KB); MFMA phase: wave w owns 32-oup slab, B shared by all
// waves from LDS. Gate cost paid once per element; gate(0)=0 keeps pads.
__global__ __launch_bounds__(256, 4) void k_main(
    const float* __restrict__ ws, float* __restrict__ out, int b0)
{
    __shared__ _Float16 Bs[40 * 512];      // [kl][px(64)][8] = 40 KB
    int t = threadIdx.x;
    int bid = blockIdx.x;
    int half = bid & 1, tile = (bid >> 1) & 127, bbl = bid >> 8;
    int b = b0 + bbl;
    int oh0 = (tile >> 3) << 3, ow0 = (tile & 7) << 4;

    int w = __builtin_amdgcn_readfirstlane(t >> 6);
    int lane = t & 63, quad = lane >> 4, l15 = lane & 15;

    const _Float16* Wh = (const _Float16*)(ws + WS_WH);
    const _Float16* Bimg = (const _Float16*)(ws + WS_BIMG)
        + (size_t)bbl * BIMG_BATCH_F16 + (size_t)tile * (KB_ * 1024)
        + (size_t)(half * 64 + lane) * 8;
    const float4* gp = (const float4*)(ws + WS_GATE) + b * 64;

    v4f acc[2][4];
#pragma unroll
    for (int a = 0; a < 2; ++a)
#pragma unroll
        for (int bb = 0; bb < 4; ++bb) acc[a][bb] = (v4f)0.f;

#pragma unroll 1
    for (int r = 0; r < 2; ++r) {
        if (r) __syncthreads();            // MFMA of prev round done reading Bs
        // ---- stage + gate: 40 cells, 10 per wave, 1KB/wave coalesced loads
#pragma unroll 2
        for (int i = 0; i < 10; ++i) {
            int kl = i * 4 + w;            // wave-uniform LDS cell
            int kb = r * 40 + kl;          // wave-uniform global cell
            int q5 = kb / 10;
            int cbase = q5 * 8 + (kb - q5 * 10 >= 5 ? 4 : 0);
            float4 g0 = gp[cbase], g1 = gp[cbase + 1];
            float4 g2 = gp[cbase + 2], g3 = gp[cbase + 3];
            uint4 cell = *(const uint4*)(Bimg + (size_t)kb * 1024);
            v8h v = __builtin_bit_cast(v8h, cell);
            float u[8];
#pragma unroll
            for (int e = 0; e < 8; ++e) {
                float f = (float)v[e];
                float4 g = (e & 3) == 0 ? g0 : ((e & 3) == 1 ? g1 : ((e & 3) == 2 ? g2 : g3));
                float ex = __builtin_amdgcn_exp2f(fmaf(g.z, f, g.w));
                u[e] = f * fmaf(g.y, __builtin_amdgcn_rcpf(1.f + ex), g.x);
            }
            uint4 oc;
            oc.x = pk_u32(u[0], u[1]); oc.y = pk_u32(u[2], u[3]);
            oc.z = pk_u32(u[4], u[5]); oc.w = pk_u32(u[6], u[7]);
            *(uint4*)(Bs + kl * 512 + lane * 8) = oc;   // contiguous 1KB/wave
        }
        __syncthreads();
        // ---- MFMA: 10 K-steps of 32; A from L2-hot Wh, B from LDS
#pragma unroll
        for (int s = 0; s < 10; ++s) {
            int cglob = r * 40 + s * 4 + quad;
            const _Float16* Ap = Wh + ((size_t)cglob * 128 + w * 32 + l15) * 8;
            v8h A0 = *(const v8h*)(Ap);
            v8h A1 = *(const v8h*)(Ap + 128);          // +16 oup rows
            int klq = s * 4 + quad;
            v8h Bf[4];
#pragma unroll
            for (int bb = 0; bb < 4; ++bb)
                Bf[bb] = *(const v8h*)(Bs + klq * 512 + (bb * 16 + l15) * 8);
#pragma unroll
            for (int bb = 0; bb < 4; ++bb) {
                acc[0][bb] = __builtin_amdgcn_mfma_f32_16x16x32_f16(A0, Bf[bb], acc[0][bb], 0, 0, 0);
                acc[1][bb] = __builtin_amdgcn_mfma_f32_16x16x32_f16(A1, Bf[bb], acc[1][bb], 0, 0, 0);
            }
        }
    }

    // ---- epilogue: bias + SiLU; C/D: col=lane&15(px), row=quad*4+reg(oup)
    size_t ob = (size_t)b * 128 * HW_;
#pragma unroll
    for (int a = 0; a < 2; ++a) {
#pragma unroll
        for (int r2 = 0; r2 < 4; ++r2) {
            int oup = w * 32 + a * 16 + quad * 4 + r2;
            float bo = ws[WS_BIAS + oup];
#pragma unroll
            for (int bb = 0; bb < 4; ++bb) {
                int p2 = half * 64 + bb * 16 + l15;
                int py2 = p2 >> 4, px2 = p2 & 15;
                float z = acc[a][bb][r2] + bo;
                out[ob + (size_t)oup * HW_ + (oh0 + py2) * W_ + ow0 + px2] = z * sigmf(z);
            }
        }
    }
}

extern "C" void kernel_launch(void* const* d_in, const int* in_sizes, int n_in,
                              void* d_out, int out_size, void* d_ws, size_t ws_size,
                              hipStream_t stream)
{
    const float* x      = (const float*)d_in[0];
    const float* gen_w  = (const float*)d_in[1];
    const float* gg     = (const float*)d_in[2];
    const float* gb     = (const float*)d_in[3];
    const float* gm     = (const float*)d_in[4];
    const float* gv     = (const float*)d_in[5];
    const float* gnw    = (const float*)d_in[6];
    const float* gnb    = (const float*)d_in[7];
    const float* cwt    = (const float*)d_in[8];
    const float* cbs    = (const float*)d_in[9];
    const float* swt    = (const float*)d_in[10];
    const float* sbs    = (const float*)d_in[11];
    const float* wadd   = (const float*)d_in[12];
    const float* conv_w = (const float*)d_in[13];
    const float* cg2    = (const float*)d_in[14];
    const float* cb2    = (const float*)d_in[15];
    const float* cm2    = (const float*)d_in[16];
    const float* cv2    = (const float*)d_in[17];
    float* ws  = (float*)d_ws;
    float* out = (float*)d_out;

    // pick the largest batch chunk whose B-image fits in ws
    size_t avail = ws_size / 4;   // floats
    int nb = 1;
    const int cands[4] = {8, 4, 2, 1};
    for (int i = 0; i < 4; ++i) {
        if ((size_t)WS_BIMG + (size_t)cands[i] * BIMG_BATCH_FLT <= avail) { nb = cands[i]; break; }
    }

    k_fold<<<343, 256, 0, stream>>>(gen_w, gg, gb, gm, gv, conv_w, cg2, cb2, cm2, cv2, ws);
    for (int b0 = 0; b0 < 8; b0 += nb) {
        k_conv<<<nb * 1024, 256, 0, stream>>>(x, ws, b0);
        k_gate<<<(nb * 64 + 255) / 256, 256, 0, stream>>>(
            ws + WS_PART, cwt, cbs, swt, sbs, gnw, gnb, wadd,
            (float4*)(ws + WS_GATE), b0, nb);
        k_main<<<nb * 256, 256, 0, stream>>>(ws, out, b0);
    }
}